// Round 5
// baseline (2786.101 us; speedup 1.0000x reference)
//
#include <hip/hip_runtime.h>
#include <cstdint>
#include <cstddef>

typedef __bf16 bf16x8 __attribute__((ext_vector_type(8)));
typedef float f32x4 __attribute__((ext_vector_type(4)));

#define HD 256
#define TLEN 1000
#define NSTEP 999
#define BTILE 4

// ws layout (bf16 elements): W1R | W2R | W3R | W4R, fragment-ordered
#define W1R_OFF 0
#define W2R_OFF 16384
#define W3R_OFF 81920
#define W4R_OFF 147456
#define WS_ELEMS 151552

__device__ __forceinline__ void wg_barrier() {
  // LDS-only drain + barrier: do NOT force vmcnt(0) like __syncthreads does,
  // so the z-prefetch / out-stores stay in flight across layer barriers.
  asm volatile("s_waitcnt lgkmcnt(0)\n\ts_barrier" ::: "memory");
}

// Repack fp32 weights -> bf16 MFMA A-fragments in ws (v0 layout).
// Fragment element for (w,kb,tt,lane,j): k = kb*32 + (lane>>4)*8 + j ; n = w*32 + tt*16 + (lane&15)
// value = W[k][n] (b1 folded into W1 padded row k==48).
__global__ void prep_weights(const float* __restrict__ W1, const float* __restrict__ b1,
                             const float* __restrict__ W2, const float* __restrict__ W3,
                             const float* __restrict__ W4, __bf16* __restrict__ ws) {
  int tid = blockIdx.x * blockDim.x + threadIdx.x;
  if (tid >= WS_ELEMS) return;
  float val = 0.0f;
  if (tid < W2R_OFF) {                       // W1R: 8w x 2kb x 2tt x 64lane x 8j
    int t = tid;
    int j = t & 7, lane = (t >> 3) & 63, tt = (t >> 9) & 1, kb = (t >> 10) & 1, w = (t >> 11) & 7;
    int k = kb * 32 + ((lane >> 4) * 8) + j;
    int n = w * 32 + tt * 16 + (lane & 15);
    if (k < 48) val = W1[k * HD + n];
    else if (k == 48) val = b1[n];           // bias folded via constant-1 input at k=48
  } else if (tid < W3R_OFF) {                // W2R: 8w x 8kb x 2tt x 64 x 8
    int t = tid - W2R_OFF;
    int j = t & 7, lane = (t >> 3) & 63, tt = (t >> 9) & 1, kb = (t >> 10) & 7, w = (t >> 13) & 7;
    int k = kb * 32 + ((lane >> 4) * 8) + j;
    int n = w * 32 + tt * 16 + (lane & 15);
    val = W2[k * HD + n];
  } else if (tid < W4R_OFF) {                // W3R
    int t = tid - W3R_OFF;
    int j = t & 7, lane = (t >> 3) & 63, tt = (t >> 9) & 1, kb = (t >> 10) & 7, w = (t >> 13) & 7;
    int k = kb * 32 + ((lane >> 4) * 8) + j;
    int n = w * 32 + tt * 16 + (lane & 15);
    val = W3[k * HD + n];
  } else {                                   // W4R: 8kb x 64 x 8, N padded 8->16 with zeros
    int t = tid - W4R_OFF;
    int j = t & 7, lane = (t >> 3) & 63, kb = (t >> 9) & 7;
    int k = kb * 32 + ((lane >> 4) * 8) + j;
    int n = lane & 15;
    val = (n < 8) ? W4[k * 8 + n] : 0.0f;
  }
  ws[tid] = (__bf16)val;
}

// r4 localized the bottleneck: critical-path latency (4 barriers + serial
// wave-0 reduce + x/z LDS round trips), NOT LDS bandwidth. This version keeps
// v4's phase 1-3 byte-identical and removes the latency tail:
//  - layer 4 full-K REDUNDANT in every wave (w4f[8]; masked hC read is only
//    2 KB/wave at BTILE=4 — v1's 64 KB failure mode doesn't apply)
//  - Euler per-lane in registers; all waves write identical x_cur/z_eff values
//    (benign same-value race); next phase 1 reads them SAME-WAVE -> no barrier
//  - 3 barriers/step, no serial single-wave section, triple-buffered h.
__global__ __launch_bounds__(512, 2) void ode_main(
    const float* __restrict__ t_g, const float* __restrict__ x_g,
    const float* __restrict__ z_g, const float* __restrict__ ev_g,
    const float* __restrict__ zj_g, const float* __restrict__ b2_g,
    const float* __restrict__ b3_g, const float* __restrict__ b4_g,
    const __bf16* __restrict__ ws, float* __restrict__ out) {
  // L1->hA, L2: hA->hB, L3: hB->hC, L4 reads hC (full, all waves).
  // Every h WAR pair is separated by >=2 of the 3 barriers (incl. across steps).
  __shared__ __align__(16) __bf16 h_a[16 * 264];
  __shared__ __align__(16) __bf16 h_b[16 * 264];
  __shared__ __align__(16) __bf16 h_c[16 * 264];
  __shared__ __align__(16) float x_cur[16 * 12];
  __shared__ __align__(16) float z_eff[16 * 12];
  __shared__ __align__(16) float x0s[16 * 12];
  __shared__ __align__(16) float z0s[16 * 12];
  __shared__ __align__(16) float zjs[16 * 12];
  __shared__ float evs[16];

  const int tid  = threadIdx.x;
  const int lane = tid & 63;
  const int wid  = tid >> 6;     // 8 waves; wave w owns hidden cols [32w, 32w+32)
  const int bcol = lane & 15;    // B/C-operand column; batch row if < BTILE, dead otherwise
  const int q    = lane >> 4;    // quad
  const int b0   = blockIdx.x * BTILE;
  const bool live = bcol < BTILE;
  const size_t gb = (size_t)(b0 + (live ? bcol : 0));  // stores masked by `live`

  // ---- stage per-batch constants (rows >= BTILE zeroed: dead cols stay exact 0) ----
  if (tid < 128) {
    int m = tid >> 3, d = tid & 7;
    if (m < BTILE) {
      size_t g = (size_t)(b0 + m);
      float x0 = x_g[g * (TLEN * 8) + d];
      float z0 = z_g[g * (TLEN * 8) + d];
      x0s[m * 12 + d] = x0;
      z0s[m * 12 + d] = z0;
      x_cur[m * 12 + d] = x0;
      zjs[m * 12 + d] = zj_g[g * 8 + d];
      out[g * (TLEN * 8) + d] = x0;          // sol[:,0] = x0
      if (d == 0) evs[m] = ev_g[g];
    } else {
      x0s[m * 12 + d] = 0.f;
      z0s[m * 12 + d] = 0.f;
      x_cur[m * 12 + d] = 0.f;
      zjs[m * 12 + d] = 0.f;
      if (d == 0) evs[m] = 0.f;
    }
  }
  __syncthreads();

  if (tid < 128) {  // z_eff for step 0 (rows >= BTILE resolve to 0)
    int m = tid >> 3, d = tid & 7;
    float t0 = t_g[0];
    z_eff[m * 12 + d] = (t0 >= evs[m]) ? zjs[m * 12 + d] : z0s[m * 12 + d];
  }

  // ---- resident weight fragments (A-operand layout) ----
  const bf16x8* wsv = (const bf16x8*)ws;
  bf16x8 w1f[2][2], w2f[8][2], w3f[8][2], w4f[8];
#pragma unroll
  for (int kb = 0; kb < 2; ++kb)
#pragma unroll
    for (int tt = 0; tt < 2; ++tt)
      w1f[kb][tt] = wsv[(W1R_OFF / 8) + ((wid * 2 + kb) * 2 + tt) * 64 + lane];
#pragma unroll
  for (int kb = 0; kb < 8; ++kb) {
#pragma unroll
    for (int tt = 0; tt < 2; ++tt) {
      w2f[kb][tt] = wsv[(W2R_OFF / 8) + ((wid * 8 + kb) * 2 + tt) * 64 + lane];
      w3f[kb][tt] = wsv[(W3R_OFF / 8) + ((wid * 8 + kb) * 2 + tt) * 64 + lane];
    }
    w4f[kb] = wsv[(W4R_OFF / 8) + kb * 64 + lane];  // ALL k-slices: full-K L4 per wave
  }

  // biases as C-init: lane's 4 C rows are hidden n = wid*32 + tt*16 + q*4 + e
  f32x4 b2v[2], b3v[2];
#pragma unroll
  for (int tt = 0; tt < 2; ++tt) {
    int n0 = wid * 32 + tt * 16 + q * 4;
    b2v[tt] = *(const f32x4*)(b2_g + n0);
    b3v[tt] = *(const f32x4*)(b3_g + n0);
  }
  f32x4 b4v = {0.f, 0.f, 0.f, 0.f};
  if (q < 2) b4v = *(const f32x4*)(b4_g + q * 4);   // C rows q*4+e < 8 are the live out dims

  // z_eff producer personals — EVERY wave, lanes 0..15: (m 0..3) x (d pairs)
  const int m1 = lane >> 2;
  const int d0 = (lane & 3) * 2;
  const bool zp = (lane < 16);
  float2 zjf = make_float2(0.f, 0.f);
  float ev1 = 0.f;
  if (zp) {
    zjf.x = zjs[m1 * 12 + d0];
    zjf.y = zjs[m1 * 12 + d0 + 1];
    ev1 = evs[m1];
  }

  // layer-1 per-lane B-frag constants:
  // q=0: k=0..7   -> x0 (const)          q=1: k=8..15  -> z0 (const)
  // q=2: k=16..23 -> x_cur - x0          q=3: k=24..31 -> z_eff - z0
  f32x4 sub0, sub1;
  bf16x8 a0c;
  {
    const float* base = ((q & 1) ? z0s : x0s) + bcol * 12;
    f32x4 r0 = *(const f32x4*)(base);
    f32x4 r1 = *(const f32x4*)(base + 4);
    sub0 = r0; sub1 = r1;
#pragma unroll
    for (int e = 0; e < 4; ++e) { a0c[e] = (__bf16)r0[e]; a0c[e + 4] = (__bf16)r1[e]; }
  }
  bf16x8 zf;
#pragma unroll
  for (int e = 0; e < 8; ++e) zf[e] = (__bf16)0.f;
  bf16x8 k48f = zf;
  k48f[0] = (__bf16)1.0f;  // constant-1 input at padded k=48 -> adds b1

  // per-lane x state: lane (q<2, bcol) owns x[bcol][q*4 .. q*4+3] (rows>=BTILE stay 0)
  f32x4 xc4 = {0.f, 0.f, 0.f, 0.f};
  if (q < 2) xc4 = *(const f32x4*)(x0s + bcol * 12 + q * 4);

  __syncthreads();

  float tc = t_g[0];

  // persistent masked-read destinations: dead lanes keep zeros forever.
  bf16x8 bfr[8];
#pragma unroll
  for (int kb = 0; kb < 8; ++kb) bfr[kb] = zf;

  auto layer = [&](const __bf16* src, __bf16* dst, const bf16x8 (*wf)[2], const f32x4* bv) {
    const bf16x8* hp = (const bf16x8*)src;
    if (live) {   // masked reads: dead lanes generate no LDS traffic
#pragma unroll
      for (int kb = 0; kb < 8; ++kb) bfr[kb] = hp[bcol * 33 + kb * 4 + q];  // ds_read_b128 x8
    }
#pragma unroll
    for (int tt = 0; tt < 2; ++tt) {
      f32x4 c = bv[tt];
#pragma unroll
      for (int kb = 0; kb < 8; ++kb)
        c = __builtin_amdgcn_mfma_f32_16x16x32_bf16(wf[kb][tt], bfr[kb], c, 0, 0, 0);
      union { __bf16 h4[4]; unsigned long long u; } pk;
#pragma unroll
      for (int e = 0; e < 4; ++e) {
        float v = c[e];
        v = (v > 0.f) ? v : (__expf(v) - 1.0f);  // ELU
        pk.h4[e] = (__bf16)v;
      }
      if (live)
        *(unsigned long long*)(dst + bcol * 264 + wid * 32 + tt * 16 + q * 4) = pk.u;
    }
  };

#pragma unroll 1
  for (int i = 0; i < NSTEP; ++i) {
    float tn = t_g[i + 1];
    float2 zpre = make_float2(0.f, 0.f);
    if (zp)  // every wave prefetches its own copy of z[:, i+1] (tiny, L2-hit)
      zpre = *(const float2*)(z_g + ((size_t)(b0 + m1) * TLEN + (i + 1)) * 8 + d0);

    // ---- phase 1: layer 1 (K padded 48->64, bias via k=48) ----
    // x_cur/z_eff were written by THIS wave in phase 4 of step i-1 -> same-wave
    // LDS RAW, ordered by lgkmcnt, no barrier needed.
    {
      const float* rp = ((q & 1) ? z_eff : x_cur) + bcol * 12;
      f32x4 r0 = *(const f32x4*)(rp);
      f32x4 r1 = *(const f32x4*)(rp + 4);
      bf16x8 f0, f1;
      if (q < 2) {
        f0 = a0c;
#pragma unroll
        for (int e = 0; e < 4; ++e) { f1[e] = (__bf16)r0[e]; f1[e + 4] = (__bf16)r1[e]; }
      } else {
#pragma unroll
        for (int e = 0; e < 4; ++e) {
          f0[e] = (__bf16)(r0[e] - sub0[e]);
          f0[e + 4] = (__bf16)(r1[e] - sub1[e]);
        }
        f1 = (q == 2) ? k48f : zf;
      }
#pragma unroll
      for (int tt = 0; tt < 2; ++tt) {
        f32x4 c = {0.f, 0.f, 0.f, 0.f};
        c = __builtin_amdgcn_mfma_f32_16x16x32_bf16(w1f[0][tt], f0, c, 0, 0, 0);
        c = __builtin_amdgcn_mfma_f32_16x16x32_bf16(w1f[1][tt], f1, c, 0, 0, 0);
        union { __bf16 h4[4]; unsigned long long u; } pk;
#pragma unroll
        for (int e = 0; e < 4; ++e) {
          float v = c[e];
          v = (v > 0.f) ? v : (__expf(v) - 1.0f);
          pk.h4[e] = (__bf16)v;
        }
        if (live)
          *(unsigned long long*)(h_a + bcol * 264 + wid * 32 + tt * 16 + q * 4) = pk.u;
      }
    }
    wg_barrier();
    layer(h_a, h_b, w2f, b2v);   // phase 2: layer 2
    wg_barrier();
    layer(h_b, h_c, w3f, b3v);   // phase 3: layer 3 -> hC
    wg_barrier();

    // ---- phase 4: layer 4 full-K REDUNDANT per wave; Euler per-lane; no barrier.
    // All waves write IDENTICAL x_cur/z_eff values (deterministic MFMA on
    // identical inputs) -> same-value LDS races are benign.
    {
      const bf16x8* hp = (const bf16x8*)h_c;
      if (live) {
#pragma unroll
        for (int kb = 0; kb < 8; ++kb) bfr[kb] = hp[bcol * 33 + kb * 4 + q];
      }
      f32x4 c0 = {0.f, 0.f, 0.f, 0.f}, c1 = {0.f, 0.f, 0.f, 0.f};
#pragma unroll
      for (int kb = 0; kb < 4; ++kb)
        c0 = __builtin_amdgcn_mfma_f32_16x16x32_bf16(w4f[kb], bfr[kb], c0, 0, 0, 0);
#pragma unroll
      for (int kb = 4; kb < 8; ++kb)
        c1 = __builtin_amdgcn_mfma_f32_16x16x32_bf16(w4f[kb], bfr[kb], c1, 0, 0, 0);
      float dt = tn - tc;
      if (q < 2) {
        f32x4 xn;
#pragma unroll
        for (int e = 0; e < 4; ++e) xn[e] = xc4[e] + dt * (c0[e] + c1[e] + b4v[e]);
        xc4 = xn;
        if (live) {
          *(f32x4*)(x_cur + bcol * 12 + q * 4) = xn;
          if (wid == 0)   // fire-and-forget global store (no vmcnt at barriers)
            *(f32x4*)(out + gb * (TLEN * 8) + (size_t)(i + 1) * 8 + q * 4) = xn;
        }
      }
      if (zp) {
        bool jmp = (tn >= ev1);
        float2 zev = make_float2(jmp ? zjf.x : zpre.x, jmp ? zjf.y : zpre.y);
        *(float2*)(z_eff + m1 * 12 + d0) = zev;
      }
    }
    tc = tn;
  }
}

extern "C" void kernel_launch(void* const* d_in, const int* in_sizes, int n_in,
                              void* d_out, int out_size, void* d_ws, size_t ws_size,
                              hipStream_t stream) {
  const float* t  = (const float*)d_in[0];
  const float* x  = (const float*)d_in[1];
  const float* z  = (const float*)d_in[2];
  const float* ev = (const float*)d_in[3];
  const float* zj = (const float*)d_in[4];
  const float* W1 = (const float*)d_in[5];
  const float* b1 = (const float*)d_in[6];
  const float* W2 = (const float*)d_in[7];
  const float* b2 = (const float*)d_in[8];
  const float* W3 = (const float*)d_in[9];
  const float* b3 = (const float*)d_in[10];
  const float* W4 = (const float*)d_in[11];
  const float* b4 = (const float*)d_in[12];
  __bf16* ws = (__bf16*)d_ws;
  float* out = (float*)d_out;

  prep_weights<<<592, 256, 0, stream>>>(W1, b1, W2, W3, W4, ws);
  ode_main<<<256, 512, 0, stream>>>(t, x, z, ev, zj, b2, b3, b4, ws, out);
}

// Round 6
// 2252.026 us; speedup vs baseline: 1.2372x; 1.2372x over previous
//
#include <hip/hip_runtime.h>
#include <cstdint>
#include <cstddef>

typedef __bf16 bf16x8 __attribute__((ext_vector_type(8)));
typedef float f32x4 __attribute__((ext_vector_type(4)));

#define HD 256
#define TLEN 1000
#define NSTEP 999
#define BTILE 4

// ws layout (bf16 elements): W1R | W2R | W3R | W4R, fragment-ordered
#define W1R_OFF 0
#define W2R_OFF 16384
#define W3R_OFF 81920
#define W4R_OFF 147456
#define WS_ELEMS 151552

__device__ __forceinline__ void wg_barrier() {
  // LDS-only drain + barrier: do NOT force vmcnt(0) like __syncthreads does,
  // so the z-prefetch / out-stores stay in flight across layer barriers.
  asm volatile("s_waitcnt lgkmcnt(0)\n\ts_barrier" ::: "memory");
}

// Repack fp32 weights -> bf16 MFMA A-fragments in ws (v0 layout, unchanged).
// Fragment element for (w,kb,tt,lane,j): k = kb*32 + (lane>>4)*8 + j ; n = w*32 + tt*16 + (lane&15)
// value = W[k][n] (b1 folded into W1 padded row k==48).
__global__ void prep_weights(const float* __restrict__ W1, const float* __restrict__ b1,
                             const float* __restrict__ W2, const float* __restrict__ W3,
                             const float* __restrict__ W4, __bf16* __restrict__ ws) {
  int tid = blockIdx.x * blockDim.x + threadIdx.x;
  if (tid >= WS_ELEMS) return;
  float val = 0.0f;
  if (tid < W2R_OFF) {                       // W1R: 8w x 2kb x 2tt x 64lane x 8j
    int t = tid;
    int j = t & 7, lane = (t >> 3) & 63, tt = (t >> 9) & 1, kb = (t >> 10) & 1, w = (t >> 11) & 7;
    int k = kb * 32 + ((lane >> 4) * 8) + j;
    int n = w * 32 + tt * 16 + (lane & 15);
    if (k < 48) val = W1[k * HD + n];
    else if (k == 48) val = b1[n];           // bias folded via constant-1 input at k=48
  } else if (tid < W3R_OFF) {                // W2R: 8w x 8kb x 2tt x 64 x 8
    int t = tid - W2R_OFF;
    int j = t & 7, lane = (t >> 3) & 63, tt = (t >> 9) & 1, kb = (t >> 10) & 7, w = (t >> 13) & 7;
    int k = kb * 32 + ((lane >> 4) * 8) + j;
    int n = w * 32 + tt * 16 + (lane & 15);
    val = W2[k * HD + n];
  } else if (tid < W4R_OFF) {                // W3R
    int t = tid - W3R_OFF;
    int j = t & 7, lane = (t >> 3) & 63, tt = (t >> 9) & 1, kb = (t >> 10) & 7, w = (t >> 13) & 7;
    int k = kb * 32 + ((lane >> 4) * 8) + j;
    int n = w * 32 + tt * 16 + (lane & 15);
    val = W3[k * HD + n];
  } else {                                   // W4R: 8kb x 64 x 8, N padded 8->16 with zeros
    int t = tid - W4R_OFF;
    int j = t & 7, lane = (t >> 3) & 63, kb = (t >> 9) & 7;
    int k = kb * 32 + ((lane >> 4) * 8) + j;
    int n = lane & 15;
    val = (n < 8) ? W4[k * 8 + n] : 0.0f;
  }
  ws[tid] = (__bf16)val;
}

// r4 post-mortem: per-block step latency is the wall; VALU(48%)+MFMA(31%)
// issue at only 2 waves/SIMD serialize. This version keeps r4's schedule
// (4 barriers, wave-0 reduce, wave-2 z-producer) but splits hidden 256 across
// SIXTEEN waves x 16 cols (1024 thr) -> 4 waves/SIMD: per-wave stream halves,
// VALU/MFMA cross-wave overlap doubles. Register diet to fit the 128-VGPR cap:
// broadcast rdcol reads (no persistent zero frags), consts re-read from LDS.
__global__ __launch_bounds__(1024, 4) void ode_main(
    const float* __restrict__ t_g, const float* __restrict__ x_g,
    const float* __restrict__ z_g, const float* __restrict__ ev_g,
    const float* __restrict__ zj_g, const float* __restrict__ b2_g,
    const float* __restrict__ b3_g, const float* __restrict__ b4_g,
    const __bf16* __restrict__ ws, float* __restrict__ out) {
  __shared__ __align__(16) __bf16 h_a[16 * 264];   // 16 rows kept (4 live), row 528B
  __shared__ __align__(16) __bf16 h_b[16 * 264];
  __shared__ __align__(16) float p4[16 * 128];     // [wave][bcol*8 + q*4 .. +3]
  __shared__ __align__(16) float x_cur[16 * 12];
  __shared__ __align__(16) float z_eff[16 * 12];
  __shared__ __align__(16) float x0s[16 * 12];
  __shared__ __align__(16) float z0s[16 * 12];
  __shared__ __align__(16) float zjs[16 * 12];
  __shared__ float evs[16];

  const int tid  = threadIdx.x;
  const int lane = tid & 63;
  const int wid  = tid >> 6;     // 16 waves; wave w owns hidden cols [16w, 16w+16)
  const int pw   = wid >> 1;     // prep-layout w index (32-col group)
  const int ptt  = wid & 1;      // which 16-col half of the group
  const int bcol = lane & 15;    // B/C-operand column; batch row if < BTILE
  const int rdcol= bcol & 3;     // broadcast read row (valid data for dead lanes)
  const int q    = lane >> 4;    // quad
  const int b0   = blockIdx.x * BTILE;
  const bool live = bcol < BTILE;

  // ---- stage per-batch constants (rows >= BTILE zeroed) ----
  if (tid < 128) {
    int m = tid >> 3, d = tid & 7;
    if (m < BTILE) {
      size_t g = (size_t)(b0 + m);
      float x0 = x_g[g * (TLEN * 8) + d];
      float z0 = z_g[g * (TLEN * 8) + d];
      x0s[m * 12 + d] = x0;
      z0s[m * 12 + d] = z0;
      x_cur[m * 12 + d] = x0;
      zjs[m * 12 + d] = zj_g[g * 8 + d];
      out[g * (TLEN * 8) + d] = x0;          // sol[:,0] = x0
      if (d == 0) evs[m] = ev_g[g];
    } else {
      x0s[m * 12 + d] = 0.f;
      z0s[m * 12 + d] = 0.f;
      x_cur[m * 12 + d] = 0.f;
      zjs[m * 12 + d] = 0.f;
      if (d == 0) evs[m] = 0.f;
    }
  }
  __syncthreads();

  if (tid < 128) {  // z_eff for step 0
    int m = tid >> 3, d = tid & 7;
    float t0 = t_g[0];
    z_eff[m * 12 + d] = (t0 >= evs[m]) ? zjs[m * 12 + d] : z0s[m * 12 + d];
  }

  // ---- resident weight fragments: ONE tt-slice per wave (half of r4) ----
  const bf16x8* wsv = (const bf16x8*)ws;
  bf16x8 w1f[2], w2f[8], w3f[8];
#pragma unroll
  for (int kb = 0; kb < 2; ++kb)
    w1f[kb] = wsv[(W1R_OFF / 8) + ((pw * 2 + kb) * 2 + ptt) * 64 + lane];
#pragma unroll
  for (int kb = 0; kb < 8; ++kb) {
    w2f[kb] = wsv[(W2R_OFF / 8) + ((pw * 8 + kb) * 2 + ptt) * 64 + lane];
    w3f[kb] = wsv[(W3R_OFF / 8) + ((pw * 8 + kb) * 2 + ptt) * 64 + lane];
  }
  // W4 k-block for this wave pair: kb = pw; this wave contributes only the
  // 16 k-rows it writes (half selected via B-frag zeroing below).
  bf16x8 w4f = wsv[(W4R_OFF / 8) + pw * 64 + lane];

  // biases as C-init: lane's 4 C rows are hidden n = wid*16 + q*4 + e
  f32x4 b2v = *(const f32x4*)(b2_g + wid * 16 + q * 4);
  f32x4 b3v = *(const f32x4*)(b3_g + wid * 16 + q * 4);
  float b4l = (tid < 64) ? b4_g[tid & 7] : 0.0f;

  // wave-2 personals (z_eff producer): lanes 0..15 cover (m 0..3) x (d pairs)
  const int m1 = lane >> 2;
  const int d0 = (lane & 3) * 2;
  float2 zjf = make_float2(0.f, 0.f);
  float ev1 = 0.f;
  const bool zprod = (wid == 2) && (lane < BTILE * 4);
  if (zprod) {
    zjf.x = zjs[m1 * 12 + d0];
    zjf.y = zjs[m1 * 12 + d0 + 1];
    ev1 = evs[m1];
  }

  bf16x8 zf;
#pragma unroll
  for (int e = 0; e < 8; ++e) zf[e] = (__bf16)0.f;

  __syncthreads();

  float tc = t_g[0];

  auto layer = [&](const __bf16* src, __bf16* dst, const bf16x8* wf, f32x4 bv) {
    const bf16x8* hp = (const bf16x8*)src;
    // broadcast reads: dead lanes read rdcol's (valid) data -> no exec toggle,
    // no persistent zero frags; dead B-cols feed only dead C-cols.
    bf16x8 f0 = hp[rdcol * 33 + 0 * 4 + q];
    bf16x8 f1 = hp[rdcol * 33 + 1 * 4 + q];
    bf16x8 f2 = hp[rdcol * 33 + 2 * 4 + q];
    bf16x8 f3 = hp[rdcol * 33 + 3 * 4 + q];
    bf16x8 f4 = hp[rdcol * 33 + 4 * 4 + q];
    bf16x8 f5 = hp[rdcol * 33 + 5 * 4 + q];
    bf16x8 f6 = hp[rdcol * 33 + 6 * 4 + q];
    bf16x8 f7 = hp[rdcol * 33 + 7 * 4 + q];
    // two independent 4-chains (one tt per wave now)
    f32x4 c0 = bv;
    f32x4 c1 = {0.f, 0.f, 0.f, 0.f};
    c0 = __builtin_amdgcn_mfma_f32_16x16x32_bf16(wf[0], f0, c0, 0, 0, 0);
    c1 = __builtin_amdgcn_mfma_f32_16x16x32_bf16(wf[4], f4, c1, 0, 0, 0);
    c0 = __builtin_amdgcn_mfma_f32_16x16x32_bf16(wf[1], f1, c0, 0, 0, 0);
    c1 = __builtin_amdgcn_mfma_f32_16x16x32_bf16(wf[5], f5, c1, 0, 0, 0);
    c0 = __builtin_amdgcn_mfma_f32_16x16x32_bf16(wf[2], f2, c0, 0, 0, 0);
    c1 = __builtin_amdgcn_mfma_f32_16x16x32_bf16(wf[6], f6, c1, 0, 0, 0);
    c0 = __builtin_amdgcn_mfma_f32_16x16x32_bf16(wf[3], f3, c0, 0, 0, 0);
    c1 = __builtin_amdgcn_mfma_f32_16x16x32_bf16(wf[7], f7, c1, 0, 0, 0);
    union { __bf16 h4[4]; unsigned long long u; } pk;
#pragma unroll
    for (int e = 0; e < 4; ++e) {
      float v = c0[e] + c1[e];
      v = (v > 0.f) ? v : (__expf(v) - 1.0f);  // ELU
      pk.h4[e] = (__bf16)v;
    }
    if (live)
      *(unsigned long long*)(dst + bcol * 264 + wid * 16 + q * 4) = pk.u;
  };

#pragma unroll 1
  for (int i = 0; i < NSTEP; ++i) {
    float tn = t_g[i + 1];
    float2 zpre = make_float2(0.f, 0.f);
    if (zprod)  // prefetch z[:, i+1]; consumed in phase 4 of this step
      zpre = *(const float2*)(z_g + ((size_t)(b0 + m1) * TLEN + (i + 1)) * 8 + d0);

    // ---- phase 1: layer 1 (K padded 48->64, bias via k=48) ----
    // q=0: k0..7 -> x0    q=1: k8..15 -> z0
    // q=2: k16..23 -> x_cur-x0 (+k48 const-1)   q=3: k24..31 -> z_eff-z0
    {
      const float* rp = ((q & 1) ? z_eff : x_cur) + bcol * 12;
      const float* sp = ((q & 1) ? z0s   : x0s  ) + bcol * 12;
      f32x4 r0 = *(const f32x4*)(rp);
      f32x4 r1 = *(const f32x4*)(rp + 4);
      f32x4 s0 = *(const f32x4*)(sp);
      f32x4 s1 = *(const f32x4*)(sp + 4);
      bf16x8 f0, f1;
      if (q < 2) {
#pragma unroll
        for (int e = 0; e < 4; ++e) {
          f0[e] = (__bf16)s0[e]; f0[e + 4] = (__bf16)s1[e];   // x0 / z0 (const part)
          f1[e] = (__bf16)r0[e]; f1[e + 4] = (__bf16)r1[e];   // x_cur / z_eff
        }
      } else {
#pragma unroll
        for (int e = 0; e < 4; ++e) {
          f0[e] = (__bf16)(r0[e] - s0[e]);
          f0[e + 4] = (__bf16)(r1[e] - s1[e]);
        }
        f1 = zf;
        if (q == 2) f1[0] = (__bf16)1.0f;    // constant-1 at padded k=48 -> b1
      }
      f32x4 c = {0.f, 0.f, 0.f, 0.f};
      c = __builtin_amdgcn_mfma_f32_16x16x32_bf16(w1f[0], f0, c, 0, 0, 0);
      c = __builtin_amdgcn_mfma_f32_16x16x32_bf16(w1f[1], f1, c, 0, 0, 0);
      union { __bf16 h4[4]; unsigned long long u; } pk;
#pragma unroll
      for (int e = 0; e < 4; ++e) {
        float v = c[e];
        v = (v > 0.f) ? v : (__expf(v) - 1.0f);
        pk.h4[e] = (__bf16)v;
      }
      if (live)
        *(unsigned long long*)(h_a + bcol * 264 + wid * 16 + q * 4) = pk.u;
    }
    wg_barrier();
    layer(h_a, h_b, w2f, b2v);   // phase 2: layer 2
    wg_barrier();
    layer(h_b, h_a, w3f, b3v);   // phase 3: layer 3 (h3 -> h_a)

    // ---- phase 3b (no barrier): layer-4 half-K partial on OWN 16 columns ----
    // Lanes whose q-half matches ptt read exactly the cols THIS wave wrote in
    // phase 3 (same-wave RAW); the other half's B-frag is zero -> contributes 0.
    {
      bf16x8 h4 = zf;
      if (live && ((q >> 1) == ptt))
        h4 = ((const bf16x8*)h_a)[bcol * 33 + pw * 4 + q];
      f32x4 c = {0.f, 0.f, 0.f, 0.f};
      c = __builtin_amdgcn_mfma_f32_16x16x32_bf16(w4f, h4, c, 0, 0, 0);
      if (q < 2 && live)
        *(f32x4*)(p4 + wid * 128 + bcol * 8 + q * 4) = c;
    }
    wg_barrier();

    // ---- phase 4: reduce 16 partials + Euler (wave 0), z_eff(i+1) (wave 2) ----
    float dt = tn - tc;
    if (tid < 64) {
      int m = tid >> 3, d = tid & 7;
      if (m < BTILE) {
        float s = b4l;
#pragma unroll
        for (int j = 0; j < 16; ++j) s += p4[j * 128 + m * 8 + d];
        float xn = x_cur[m * 12 + d] + dt * s;
        x_cur[m * 12 + d] = xn;
        out[(size_t)(b0 + m) * (TLEN * 8) + (size_t)(i + 1) * 8 + d] = xn;
      }
    } else if (zprod) {
      bool jmp = (tn >= ev1);
      float2 zev = make_float2(jmp ? zjf.x : zpre.x, jmp ? zjf.y : zpre.y);
      *(float2*)(z_eff + m1 * 12 + d0) = zev;
    }
    tc = tn;
    wg_barrier();
  }
}

extern "C" void kernel_launch(void* const* d_in, const int* in_sizes, int n_in,
                              void* d_out, int out_size, void* d_ws, size_t ws_size,
                              hipStream_t stream) {
  const float* t  = (const float*)d_in[0];
  const float* x  = (const float*)d_in[1];
  const float* z  = (const float*)d_in[2];
  const float* ev = (const float*)d_in[3];
  const float* zj = (const float*)d_in[4];
  const float* W1 = (const float*)d_in[5];
  const float* b1 = (const float*)d_in[6];
  const float* W2 = (const float*)d_in[7];
  const float* b2 = (const float*)d_in[8];
  const float* W3 = (const float*)d_in[9];
  const float* b3 = (const float*)d_in[10];
  const float* W4 = (const float*)d_in[11];
  const float* b4 = (const float*)d_in[12];
  __bf16* ws = (__bf16*)d_ws;
  float* out = (float*)d_out;

  prep_weights<<<592, 256, 0, stream>>>(W1, b1, W2, W3, W4, ws);
  ode_main<<<256, 1024, 0, stream>>>(t, x, z, ev, zj, b2, b3, b4, ws, out);
}